// Round 11
// baseline (331.021 us; speedup 1.0000x reference)
//
#include <hip/hip_runtime.h>
#include <hip/hip_fp16.h>
#include <math.h>

#define NN 8192
#define MM 64
#define BB 128
#define HIDC 512
#define OUTC 256
#define SEQW 63

#define GB     64        // batches per group (A = [0,64), B = [64,128))
#define CHUNKS 64        // p1: 64 blocks/batch, 128 rows each (256 thr)
#define CH2    32        // p2/p3: 32 blocks/batch, 256 rows each (256 thr)

// ---- workspace layout (float offsets) ----
#define OFF_KR    0
#define OFF_KW    8192
#define OFF_PR    16384
#define OFF_PW    17408
#define OFF_BS    18432                    // per-b 8: [2]=dd2 [3]=dkr [4]=swr
#define OFF_D     19456
#define OFF_PMSUM 27648                    // B*64*64
#define OFF_POUT  551936                   // B*32*64
#define OFF_DOTW  814080                   // B*N each below
#define OFF_DOTR  1862656
#define OFF_RN2   2911232
#define OFF_DOTD  3959808
#define OFF_WW    5008384
#define OFF_WR    6056960
#define OFF_HB    8388608                  // fp16 bank copy: B*N*M halves (134 MB)

#define ASH (NN + 352)                     // shared floats for merged stages

__device__ __forceinline__ float lrelu(float x){ return x > 0.f ? x : 0.01f*x; }
__device__ __forceinline__ float sigm(float x){ return 1.f/(1.f+__expf(-x)); }

typedef float fx4 __attribute__((ext_vector_type(4)));
__device__ __forceinline__ float4 ntload4(const float* p){
  fx4 v = __builtin_nontemporal_load((const fx4*)p);
  return make_float4(v.x, v.y, v.z, v.w);
}

__device__ __forceinline__ float2 h2f(unsigned u){
  __half2 h = *reinterpret_cast<__half2*>(&u);
  return __half22float2(h);
}

// block reduces (dynamic wave count; works for 256-thread blocks)
__device__ float block_reduce_sum(float v, float* red) {
  for (int m = 32; m >= 1; m >>= 1) v += __shfl_xor(v, m);
  int wid = threadIdx.x >> 6;
  int nw = (blockDim.x + 63) >> 6;
  if ((threadIdx.x & 63) == 0) red[wid] = v;
  __syncthreads();
  if (threadIdx.x == 0) { float s = 0.f; for (int i = 0; i < nw; ++i) s += red[i]; red[0] = s; }
  __syncthreads();
  float r = red[0];
  __syncthreads();
  return r;
}

__device__ float2 block_reduce_sum2(float2 v, float* red) {
  for (int m = 32; m >= 1; m >>= 1) { v.x += __shfl_xor(v.x, m); v.y += __shfl_xor(v.y, m); }
  int wid = threadIdx.x >> 6;
  int nw = (blockDim.x + 63) >> 6;
  if ((threadIdx.x & 63) == 0) { red[wid] = v.x; red[16 + wid] = v.y; }
  __syncthreads();
  if (threadIdx.x == 0) {
    float sx = 0.f, sy = 0.f;
    for (int i = 0; i < nw; ++i) { sx += red[i]; sy += red[16 + i]; }
    red[0] = sx; red[16] = sy;
  }
  __syncthreads();
  float2 r = make_float2(red[0], red[16]);
  __syncthreads();
  return r;
}

// ---------------- controller MLP (standalone, 512 thr) ----------------
__global__ __launch_bounds__(512) void ctrl_kernel(
    const float* __restrict__ x,
    const float* __restrict__ W0, const float* __restrict__ b0,
    const float* __restrict__ W1, const float* __restrict__ b1,
    const float* __restrict__ Wc, const float* __restrict__ bc,
    const float* __restrict__ Wr, const float* __restrict__ br,
    const float* __restrict__ Ww, const float* __restrict__ bw,
    float* __restrict__ ws)
{
  int b = blockIdx.x, t = threadIdx.x;
  __shared__ float xs[64];
  __shared__ float h0[512];
  __shared__ float h1[512];
  __shared__ float ct[256];
  __shared__ float rr[70], rw[70];
  if (t < 64) xs[t] = x[b*64 + t];
  __syncthreads();
  float acc = b0[t];
  for (int i = 0; i < 64; ++i) acc += xs[i] * W0[i*HIDC + t];
  h0[t] = lrelu(acc);
  __syncthreads();
  acc = b1[t];
  for (int i = 0; i < 512; ++i) acc += h0[i] * W1[i*HIDC + t];
  h1[t] = lrelu(acc);
  __syncthreads();
  if (t < 256) {
    acc = bc[t];
    for (int i = 0; i < 512; ++i) acc += h1[i] * Wc[i*OUTC + t];
    ct[t] = lrelu(acc);
  }
  __syncthreads();
  if (t < 70) {
    float ar = br[t], aw = bw[t];
    for (int i = 0; i < 256; ++i) { float c = ct[i]; ar += c * Wr[i*70 + t]; aw += c * Ww[i*70 + t]; }
    rr[t] = ar; rw[t] = aw;
  }
  __syncthreads();
  if (t < 64) { ws[OFF_KR + b*64 + t] = rr[t]; ws[OFF_KW + b*64 + t] = rw[t]; }
  if (t == 0) {
    float* p = ws + OFF_PR + b*8;
    p[0] = fmaxf(rr[64], 0.f) + 1e-8f;
    p[1] = sigm(rr[65]);
    float m = fmaxf(rr[66], fmaxf(rr[67], rr[68]));
    float e0 = expf(rr[66]-m), e1 = expf(rr[67]-m), e2 = expf(rr[68]-m);
    float ss = e0+e1+e2;
    p[2] = e0/ss; p[3] = e1/ss; p[4] = e2/ss;
    p[5] = fmaxf(rr[69], 0.f) + 1.f;
    float n2 = 0.f; for (int i = 0; i < 64; ++i) n2 += rr[i]*rr[i];
    p[6] = sqrtf(n2);
  }
  if (t == 1) {
    float* p = ws + OFF_PW + b*8;
    p[0] = fmaxf(rw[64], 0.f) + 1e-8f;
    p[1] = sigm(rw[65]);
    float m = fmaxf(rw[66], fmaxf(rw[67], rw[68]));
    float e0 = expf(rw[66]-m), e1 = expf(rw[67]-m), e2 = expf(rw[68]-m);
    float ss = e0+e1+e2;
    p[2] = e0/ss; p[3] = e1/ss; p[4] = e2/ss;
    p[5] = fmaxf(rw[69], 0.f) + 1.f;
    float n2 = 0.f; for (int i = 0; i < 64; ++i) n2 += rw[i]*rw[i];
    p[6] = sqrtf(n2);
  }
}

// ================= roles (256 threads each; streaming bodies byte-identical to R10) =================

// p1: 128 rows; sh: kwS[64], krS[64], msum[64]
__device__ void role_p1(int b, int ch, int t, const float* __restrict__ bank,
                        float* __restrict__ ws, ushort* __restrict__ hbank, float* sh)
{
  float* kwS = sh; float* krS = sh + 64; float* msum = sh + 128;
  int n0 = ch << 7;
  int cg = t & 15;
  int rl = t >> 4;
  if (t < 64) { kwS[t] = ws[OFF_KW + b*64 + t]; krS[t] = ws[OFF_KR + b*64 + t]; msum[t] = 0.f; }
  __syncthreads();
  float4 kw4 = *(float4*)&kwS[cg*4];
  float4 kr4 = *(float4*)&krS[cg*4];

  float4 v[8];
  #pragma unroll
  for (int it = 0; it < 8; ++it) {
    int n = n0 + rl + it*16;
    v[it] = ntload4(&bank[((size_t)b*NN + n)*MM + cg*4]);
  }
  #pragma unroll
  for (int it = 0; it < 8; ++it) {
    int n = n0 + rl + it*16;
    __half2 ha = __floats2half2_rn(v[it].x, v[it].y);
    __half2 hb = __floats2half2_rn(v[it].z, v[it].w);
    uint2 hw;
    hw.x = *reinterpret_cast<unsigned*>(&ha);
    hw.y = *reinterpret_cast<unsigned*>(&hb);
    *(uint2*)&hbank[((size_t)b*NN + n)*MM + cg*4] = hw;
  }
  float dw[8], dr[8], r2[8];
  float m0=0.f, m1=0.f, m2=0.f, m3=0.f;
  #pragma unroll
  for (int it = 0; it < 8; ++it) {
    dw[it] = v[it].x*kw4.x + v[it].y*kw4.y + v[it].z*kw4.z + v[it].w*kw4.w;
    dr[it] = v[it].x*kr4.x + v[it].y*kr4.y + v[it].z*kr4.z + v[it].w*kr4.w;
    r2[it] = v[it].x*v[it].x + v[it].y*v[it].y + v[it].z*v[it].z + v[it].w*v[it].w;
    m0 += v[it].x; m1 += v[it].y; m2 += v[it].z; m3 += v[it].w;
  }
  #pragma unroll
  for (int m = 1; m < 16; m <<= 1) {
    #pragma unroll
    for (int it = 0; it < 8; ++it) {
      dw[it] += __shfl_xor(dw[it], m);
      dr[it] += __shfl_xor(dr[it], m);
      r2[it] += __shfl_xor(r2[it], m);
    }
  }
  if (cg == 0) {
    size_t base = (size_t)b*NN + n0 + rl;
    #pragma unroll
    for (int it = 0; it < 8; ++it) {
      ws[OFF_DOTW + base + it*16] = dw[it];
      ws[OFF_DOTR + base + it*16] = dr[it];
      ws[OFF_RN2  + base + it*16] = r2[it];
    }
  }
  atomicAdd(&msum[cg*4+0], m0);
  atomicAdd(&msum[cg*4+1], m1);
  atomicAdd(&msum[cg*4+2], m2);
  atomicAdd(&msum[cg*4+3], m3);
  __syncthreads();
  if (t < 64) ws[OFF_PMSUM + (size_t)(b*CHUNKS + ch)*64 + t] = msum[t];
}

// addr0: 256 thr, f4 ownership; sh: buf[NN], red[32], cat[128], eaS[128], dS[64]
__device__ void role_addr0(int b, int t, const float* __restrict__ wprev,
                           const float* __restrict__ Wea, const float* __restrict__ bea,
                           float* __restrict__ ws, float* sh)
{
  float* buf = sh;
  float* red = sh + NN;
  float* cat = sh + NN + 32;
  float* eaS = sh + NN + 160;
  float* dS  = sh + NN + 288;
  const size_t bN = (size_t)b*NN;
  const float4* wp4 = (const float4*)(wprev + bN);

  float lps = 0.f;
  #pragma unroll
  for (int k = 0; k < 8; ++k) {
    float4 w = wp4[t + 256*k];
    lps += w.x + w.y + w.z + w.w;
  }

  // ea prefix
  if (t < 64) {
    float s = 0.f;
    for (int ch = 0; ch < CHUNKS; ++ch) s += ws[OFF_PMSUM + ((size_t)b*CHUNKS + ch)*64 + t];
    cat[t] = s * (1.0f/NN);
  } else if (t < 128) {
    cat[t] = ws[OFF_KW + b*64 + (t-64)];
  }
  __syncthreads();
  if (t < 128) {
    float acc = bea[t];
    for (int i = 0; i < 128; ++i) acc += cat[i] * Wea[i*128 + t];
    eaS[t] = acc;
  }
  __syncthreads();
  if (t < 64) {
    float dv = eaS[64+t] - sigm(eaS[t]);
    dS[t] = dv;
    ws[OFF_D + b*64 + t] = dv;
  }
  __syncthreads();
  if (t < 64) {   // wave-0 parallel dd/dk
    float dv = dS[t];
    float dd = dv*dv;
    float dk = dv * ws[OFF_KR + b*64 + t];
    #pragma unroll
    for (int m = 32; m >= 1; m >>= 1) { dd += __shfl_xor(dd, m); dk += __shfl_xor(dk, m); }
    if (t == 0) { ws[OFF_BS + b*8 + 2] = dd; ws[OFF_BS + b*8 + 3] = dk; }
  }

  const float* prm = ws + OFF_PW + b*8;
  float beta = prm[0], g = prm[1], s0 = prm[2], s1 = prm[3], s2 = prm[4], gamma = prm[5], knorm = prm[6];

  const float4* dw4 = (const float4*)(ws + OFF_DOTW + bN);
  const float4* rn4 = (const float4*)(ws + OFF_RN2  + bN);
  float lsum = 0.f;
  #pragma unroll
  for (int k = 0; k < 8; ++k) {
    int g4 = t + 256*k;
    float4 dw = dw4[g4], rn = rn4[g4];
    float4 e;
    e.x = __expf(beta * (dw.x / fmaxf(sqrtf(rn.x)*knorm, 1e-8f) - 1.f));
    e.y = __expf(beta * (dw.y / fmaxf(sqrtf(rn.y)*knorm, 1e-8f) - 1.f));
    e.z = __expf(beta * (dw.z / fmaxf(sqrtf(rn.z)*knorm, 1e-8f) - 1.f));
    e.w = __expf(beta * (dw.w / fmaxf(sqrtf(rn.w)*knorm, 1e-8f) - 1.f));
    lsum += e.x + e.y + e.z + e.w;
    *(float4*)&buf[4*g4] = e;
  }
  float2 se = block_reduce_sum2(make_float2(lps, lsum), red);
  float ie = g/se.y, ip = (1.f-g)/se.x;
  #pragma unroll
  for (int k = 0; k < 8; ++k) {
    int g4 = t + 256*k;
    float4 w = wp4[g4];
    float4 e = *(float4*)&buf[4*g4];
    e.x = e.x*ie + w.x*ip; e.y = e.y*ie + w.y*ip;
    e.z = e.z*ie + w.z*ip; e.w = e.w*ie + w.w*ip;
    *(float4*)&buf[4*g4] = e;
  }
  __syncthreads();
  float l2 = 0.f;
  float4 pv[8];
  #pragma unroll
  for (int k = 0; k < 8; ++k) {
    int g4 = t + 256*k;
    float4 e = *(float4*)&buf[4*g4];
    float left  = buf[(4*g4 + NN - 1) & (NN-1)];
    float right = buf[(4*g4 + 4) & (NN-1)];
    float4 p;
    p.x = exp2f(gamma * log2f(s0*left + s1*e.x + s2*e.y));
    p.y = exp2f(gamma * log2f(s0*e.x + s1*e.y + s2*e.z));
    p.z = exp2f(gamma * log2f(s0*e.y + s1*e.z + s2*e.w));
    p.w = exp2f(gamma * log2f(s0*e.z + s1*e.w + s2*right));
    pv[k] = p;
    l2 += p.x + p.y + p.z + p.w;
  }
  float wpsum = block_reduce_sum(l2, red);
  float invp = 1.f/wpsum;
  float4* wwout = (float4*)(ws + OFF_WW + bN);
  #pragma unroll
  for (int k = 0; k < 8; ++k) {
    float4 p = pv[k];
    p.x *= invp; p.y *= invp; p.z *= invp; p.w *= invp;
    wwout[t + 256*k] = p;
  }
}

// p2h: 256 rows; sh: dS[64]
__device__ void role_p2h(int b, int ch, int t, const ushort* __restrict__ hb,
                         float* __restrict__ ws, float* sh)
{
  float* dS = sh;
  int n0 = ch << 8;
  int cg = t & 7;
  int rl = t >> 3;
  if (t < 64) dS[t] = ws[OFF_D + b*64 + t];
  __syncthreads();
  float d8[8];
  #pragma unroll
  for (int j = 0; j < 8; ++j) d8[j] = dS[cg*8 + j];

  uint4 hv[8];
  #pragma unroll
  for (int it = 0; it < 8; ++it) {
    int n = n0 + rl + it*32;
    hv[it] = *(const uint4*)&hb[((size_t)b*NN + n)*MM + cg*8];
  }
  float dd[8];
  #pragma unroll
  for (int it = 0; it < 8; ++it) {
    float2 f0 = h2f(hv[it].x), f1 = h2f(hv[it].y), f2 = h2f(hv[it].z), f3 = h2f(hv[it].w);
    dd[it] = f0.x*d8[0] + f0.y*d8[1] + f1.x*d8[2] + f1.y*d8[3]
           + f2.x*d8[4] + f2.y*d8[5] + f3.x*d8[6] + f3.y*d8[7];
  }
  #pragma unroll
  for (int m = 1; m < 8; m <<= 1) {
    #pragma unroll
    for (int it = 0; it < 8; ++it) dd[it] += __shfl_xor(dd[it], m);
  }
  if (cg == 0) {
    size_t base = (size_t)b*NN + n0 + rl;
    #pragma unroll
    for (int it = 0; it < 8; ++it) ws[OFF_DOTD + base + it*32] = dd[it];
  }
}

// addr1: 256 thr, f4 ownership; sh: buf[NN], red[32]
__device__ void role_addr1(int b, int t, const float* __restrict__ wprev,
                           float* __restrict__ ws, float* sh)
{
  float* buf = sh;
  float* red = sh + NN;
  const size_t bN = (size_t)b*NN;
  const float4* wp4 = (const float4*)(wprev + bN);

  float lps = 0.f;
  #pragma unroll
  for (int k = 0; k < 8; ++k) {
    float4 w = wp4[t + 256*k];
    lps += w.x + w.y + w.z + w.w;
  }

  const float* prm = ws + OFF_PR + b*8;
  float beta = prm[0], g = prm[1], s0 = prm[2], s1 = prm[3], s2 = prm[4], gamma = prm[5], knorm = prm[6];
  float dd2 = ws[OFF_BS + b*8 + 2], dkr = ws[OFF_BS + b*8 + 3];

  const float4* ww4 = (const float4*)(ws + OFF_WW  + bN);
  const float4* dr4 = (const float4*)(ws + OFF_DOTR + bN);
  const float4* rn4 = (const float4*)(ws + OFF_RN2  + bN);
  const float4* dd4 = (const float4*)(ws + OFF_DOTD + bN);

  float lsum = 0.f;
  #pragma unroll
  for (int k = 0; k < 8; ++k) {
    int g4 = t + 256*k;
    float4 w = ww4[g4], dr = dr4[g4], rn = rn4[g4], dd = dd4[g4];
    float4 e;
    {
      float dot = dr.x + w.x*dkr;
      float r2 = fmaxf(rn.x + 2.f*w.x*dd.x + w.x*w.x*dd2, 0.f);
      e.x = __expf(beta * (dot / fmaxf(sqrtf(r2)*knorm, 1e-8f) - 1.f));
      dot = dr.y + w.y*dkr;
      r2 = fmaxf(rn.y + 2.f*w.y*dd.y + w.y*w.y*dd2, 0.f);
      e.y = __expf(beta * (dot / fmaxf(sqrtf(r2)*knorm, 1e-8f) - 1.f));
      dot = dr.z + w.z*dkr;
      r2 = fmaxf(rn.z + 2.f*w.z*dd.z + w.z*w.z*dd2, 0.f);
      e.z = __expf(beta * (dot / fmaxf(sqrtf(r2)*knorm, 1e-8f) - 1.f));
      dot = dr.w + w.w*dkr;
      r2 = fmaxf(rn.w + 2.f*w.w*dd.w + w.w*w.w*dd2, 0.f);
      e.w = __expf(beta * (dot / fmaxf(sqrtf(r2)*knorm, 1e-8f) - 1.f));
    }
    lsum += e.x + e.y + e.z + e.w;
    *(float4*)&buf[4*g4] = e;
  }
  float2 se = block_reduce_sum2(make_float2(lps, lsum), red);
  float ie = g/se.y, ip = (1.f-g)/se.x;
  #pragma unroll
  for (int k = 0; k < 8; ++k) {
    int g4 = t + 256*k;
    float4 w = wp4[g4];
    float4 e = *(float4*)&buf[4*g4];
    e.x = e.x*ie + w.x*ip; e.y = e.y*ie + w.y*ip;
    e.z = e.z*ie + w.z*ip; e.w = e.w*ie + w.w*ip;
    *(float4*)&buf[4*g4] = e;
  }
  __syncthreads();
  float l2 = 0.f, lswr = 0.f;
  float4 pv[8];
  #pragma unroll
  for (int k = 0; k < 8; ++k) {
    int g4 = t + 256*k;
    float4 e = *(float4*)&buf[4*g4];
    float left  = buf[(4*g4 + NN - 1) & (NN-1)];
    float right = buf[(4*g4 + 4) & (NN-1)];
    float4 p;
    p.x = exp2f(gamma * log2f(s0*left + s1*e.x + s2*e.y));
    p.y = exp2f(gamma * log2f(s0*e.x + s1*e.y + s2*e.z));
    p.z = exp2f(gamma * log2f(s0*e.y + s1*e.z + s2*e.w));
    p.w = exp2f(gamma * log2f(s0*e.z + s1*e.w + s2*right));
    pv[k] = p;
    l2 += p.x + p.y + p.z + p.w;
    float4 w = ww4[g4];                          // L2-hot re-load
    lswr += p.x*w.x + p.y*w.y + p.z*w.z + p.w*w.w;
  }
  float2 ps = block_reduce_sum2(make_float2(l2, lswr), red);
  float invp = 1.f/ps.x;
  float4* wrout = (float4*)(ws + OFF_WR + bN);
  #pragma unroll
  for (int k = 0; k < 8; ++k) {
    float4 p = pv[k];
    p.x *= invp; p.y *= invp; p.z *= invp; p.w *= invp;
    wrout[t + 256*k] = p;
  }
  if (t == 0) ws[OFF_BS + b*8 + 4] = ps.y * invp;
}

// p3h: 256 rows -> POUT partial; sh: osum[64]
__device__ void role_p3h(int b, int ch, int t, const ushort* __restrict__ hb,
                         float* __restrict__ ws, float* sh)
{
  float* osum = sh;
  int n0 = ch << 8;
  int cg = t & 7, rl = t >> 3;
  if (t < 64) osum[t] = 0.f;
  __syncthreads();

  float wrv[8];
  #pragma unroll
  for (int it = 0; it < 8; ++it)
    wrv[it] = ws[OFF_WR + (size_t)b*NN + n0 + rl + it*32];
  uint4 hv[8];
  #pragma unroll
  for (int it = 0; it < 8; ++it) {
    int n = n0 + rl + it*32;
    hv[it] = *(const uint4*)&hb[((size_t)b*NN + n)*MM + cg*8];
  }
  float a[8];
  #pragma unroll
  for (int j = 0; j < 8; ++j) a[j] = 0.f;
  #pragma unroll
  for (int it = 0; it < 8; ++it) {
    float2 f0 = h2f(hv[it].x), f1 = h2f(hv[it].y), f2 = h2f(hv[it].z), f3 = h2f(hv[it].w);
    float w = wrv[it];
    a[0] += w*f0.x; a[1] += w*f0.y; a[2] += w*f1.x; a[3] += w*f1.y;
    a[4] += w*f2.x; a[5] += w*f2.y; a[6] += w*f3.x; a[7] += w*f3.y;
  }
  #pragma unroll
  for (int m = 8; m < 64; m <<= 1) {
    #pragma unroll
    for (int j = 0; j < 8; ++j) a[j] += __shfl_xor(a[j], m);
  }
  if ((t & 56) == 0) {
    #pragma unroll
    for (int j = 0; j < 8; ++j) atomicAdd(&osum[cg*8 + j], a[j]);
  }
  __syncthreads();
  if (t < 64) ws[OFF_POUT + (size_t)(b*CH2 + ch)*64 + t] = osum[t];
}

// final head, 256 thr; sh: o[64], seq[512]
__device__ void role_final(int b, int t,
                           const float* __restrict__ Wsp, const float* __restrict__ bsp,
                           const float* __restrict__ Wo,  const float* __restrict__ bo,
                           float* __restrict__ out, float* __restrict__ ws, float* sh)
{
  float* o = sh; float* seq = sh + 64;
  if (t < 64) {
    float s = 0.f;
    for (int ch = 0; ch < CH2; ++ch) s += ws[OFF_POUT + ((size_t)b*CH2 + ch)*64 + t];
    float swr = ws[OFF_BS + b*8 + 4];
    o[t] = s + swr * ws[OFF_D + b*64 + t];
  }
  __syncthreads();
  #pragma unroll
  for (int r = 0; r < 2; ++r) {
    int idx = t + 256*r;
    float acc = bsp[idx];
    for (int i = 0; i < 64; ++i) acc += o[i] * Wsp[i*HIDC + idx];
    seq[idx] = lrelu(acc);
  }
  __syncthreads();
  if (t < SEQW) {
    float a = bo[t];
    for (int i = 0; i < HIDC; ++i) a += seq[i] * Wo[i*SEQW + t];
    out[b*SEQW + t] = sigm(a);
  }
}

// ================= stages =================

__global__ __launch_bounds__(256, 4) void stage1(const float* __restrict__ bank,
                                                 float* __restrict__ ws, ushort* __restrict__ hb)
{ // p1(A)
  __shared__ float sh[192];
  role_p1(blockIdx.x >> 6, blockIdx.x & 63, threadIdx.x, bank, ws, hb, sh);
}

__global__ __launch_bounds__(256, 4) void stage2(const float* __restrict__ bank,
                                                 const float* __restrict__ wwp,
                                                 const float* __restrict__ Wea, const float* __restrict__ bea,
                                                 float* __restrict__ ws, ushort* __restrict__ hb)
{ // addr0(A) || p1(B)
  __shared__ float sh[ASH];
  int blk = blockIdx.x, t = threadIdx.x;
  if (blk < GB) role_addr0(blk, t, wwp, Wea, bea, ws, sh);
  else { int gb = blk - GB; role_p1(GB + (gb >> 6), gb & 63, t, bank, ws, hb, sh); }
}

__global__ __launch_bounds__(256, 4) void stage3(const ushort* __restrict__ hb,
                                                 const float* __restrict__ wwp,
                                                 const float* __restrict__ Wea, const float* __restrict__ bea,
                                                 float* __restrict__ ws)
{ // addr0(B) || p2h(A, reversed)
  __shared__ float sh[ASH];
  int blk = blockIdx.x, t = threadIdx.x;
  if (blk < GB) role_addr0(GB + blk, t, wwp, Wea, bea, ws, sh);
  else { int gb = blk - GB; role_p2h((GB-1) - (gb >> 5), gb & 31, t, hb, ws, sh); }
}

__global__ __launch_bounds__(256, 4) void stage4(const ushort* __restrict__ hb,
                                                 const float* __restrict__ wrp,
                                                 float* __restrict__ ws)
{ // addr1(A) || p2h(B, reversed)
  __shared__ float sh[ASH];
  int blk = blockIdx.x, t = threadIdx.x;
  if (blk < GB) role_addr1(blk, t, wrp, ws, sh);
  else { int gb = blk - GB; role_p2h((BB-1) - (gb >> 5), gb & 31, t, hb, ws, sh); }
}

__global__ __launch_bounds__(256, 4) void stage5(const ushort* __restrict__ hb,
                                                 const float* __restrict__ wrp,
                                                 float* __restrict__ ws)
{ // addr1(B) || p3h(A)
  __shared__ float sh[ASH];
  int blk = blockIdx.x, t = threadIdx.x;
  if (blk < GB) role_addr1(GB + blk, t, wrp, ws, sh);
  else { int gb = blk - GB; role_p3h(gb >> 5, gb & 31, t, hb, ws, sh); }
}

__global__ __launch_bounds__(256, 4) void stage6(const ushort* __restrict__ hb,
                                                 const float* __restrict__ Wsp, const float* __restrict__ bsp,
                                                 const float* __restrict__ Wo,  const float* __restrict__ bo,
                                                 float* __restrict__ out, float* __restrict__ ws)
{ // final(A) || p3h(B)
  __shared__ float sh[640];
  int blk = blockIdx.x, t = threadIdx.x;
  if (blk < GB) role_final(blk, t, Wsp, bsp, Wo, bo, out, ws, sh);
  else { int gb = blk - GB; role_p3h(GB + (gb >> 5), gb & 31, t, hb, ws, sh); }
}

__global__ __launch_bounds__(256) void stage7(const float* __restrict__ Wsp, const float* __restrict__ bsp,
                                              const float* __restrict__ Wo,  const float* __restrict__ bo,
                                              float* __restrict__ out, float* __restrict__ ws)
{ // final(B)
  __shared__ float sh[640];
  role_final(GB + blockIdx.x, threadIdx.x, Wsp, bsp, Wo, bo, out, ws, sh);
}

extern "C" void kernel_launch(void* const* d_in, const int* in_sizes, int n_in,
                              void* d_out, int out_size, void* d_ws, size_t ws_size,
                              hipStream_t stream) {
  const float* x    = (const float*)d_in[0];
  const float* bank = (const float*)d_in[1];
  const float* wrp  = (const float*)d_in[2];
  const float* wwp  = (const float*)d_in[3];
  const float* W0   = (const float*)d_in[4];
  const float* b0   = (const float*)d_in[5];
  const float* W1   = (const float*)d_in[6];
  const float* b1   = (const float*)d_in[7];
  const float* Wc   = (const float*)d_in[8];
  const float* bc   = (const float*)d_in[9];
  const float* Wr   = (const float*)d_in[10];
  const float* br   = (const float*)d_in[11];
  const float* Ww   = (const float*)d_in[12];
  const float* bw   = (const float*)d_in[13];
  const float* Wea  = (const float*)d_in[14];
  const float* bea  = (const float*)d_in[15];
  const float* Wsp  = (const float*)d_in[16];
  const float* bsp  = (const float*)d_in[17];
  const float* Wo   = (const float*)d_in[18];
  const float* bo   = (const float*)d_in[19];
  float*  ws  = (float*)d_ws;
  ushort* hb  = (ushort*)(ws + OFF_HB);
  float*  out = (float*)d_out;

  ctrl_kernel<<<BB, 512, 0, stream>>>(x, W0,b0, W1,b1, Wc,bc, Wr,br, Ww,bw, ws);
  stage1<<<GB*CHUNKS,      256, 0, stream>>>(bank, ws, hb);
  stage2<<<GB + GB*CHUNKS, 256, 0, stream>>>(bank, wwp, Wea, bea, ws, hb);
  stage3<<<GB + GB*CH2,    256, 0, stream>>>(hb, wwp, Wea, bea, ws);
  stage4<<<GB + GB*CH2,    256, 0, stream>>>(hb, wrp, ws);
  stage5<<<GB + GB*CH2,    256, 0, stream>>>(hb, wrp, ws);
  stage6<<<GB + GB*CH2,    256, 0, stream>>>(hb, Wsp, bsp, Wo, bo, out, ws);
  stage7<<<GB,             256, 0, stream>>>(Wsp, bsp, Wo, bo, out, ws);
}